// Round 9
// baseline (77.792 us; speedup 1.0000x reference)
//
#include <hip/hip_runtime.h>
#include <hip/hip_bf16.h>
#include <math.h>

#define NF 64
#define NC 16
#define MAIN_BLOCKS 256
#define MAIN_WAVES  13                 // 832 thr; 3328 waves vs 3125 tiles

typedef __bf16 bf16x8 __attribute__((ext_vector_type(8)));
typedef float f32x4 __attribute__((ext_vector_type(4)));
typedef float f32x16 __attribute__((ext_vector_type(16)));
typedef unsigned int u32;

// async global->LDS, 16B/lane. LDS dest = wave-uniform base (HW adds lane*16).
__device__ __forceinline__ void stage16(const void* gsrc, void* ldst) {
    __builtin_amdgcn_global_load_lds(
        (const __attribute__((address_space(1))) u32*)gsrc,
        (__attribute__((address_space(3))) u32*)ldst,
        16, 0, 0);
}

// ---------------------------------------------------------------------------
// Kernel 1 v8 (unchanged): 4-wave cooperative Cholesky + inverse, rolled
// phase loops (L1I-resident ~13KB). See round-8 notes.
// ---------------------------------------------------------------------------
__global__ __launch_bounds__(256) void gmm_precompute(
    const float* __restrict__ cov,
    const float* __restrict__ means,
    const float* __restrict__ weights,
    __hip_bfloat16* __restrict__ g,
    float* __restrict__ t,
    float* __restrict__ Cc)
{
    const int w = threadIdx.x >> 6;   // wave 0..3: rows [16w,16w+16)
    const int c = threadIdx.x & 63;   // lane owns column c
    const int k = blockIdx.x;

    __shared__ __align__(16) float LT[NF][68];   // LT[j][r] = L[r][j]
    __shared__ float Xs[NF][65];                 // Xs[i][c] = G[i][c]
    __shared__ __align__(16) float wb2[2][68];   // ping-pong published row
    __shared__ __align__(16) float gw2[2][68];   // ping-pong published G row

    float a_loc[16];
    {
        const float* src = cov + (long)k * NF * NF + (w * 16) * NF + c;
        #pragma unroll
        for (int r = 0; r < 16; ++r)
            a_loc[r] = src[r * NF];
    }

    float rsq_loc[16];
    float logdiag = 0.0f;

    #pragma unroll 1
    for (int q = 0; q < 4; ++q) {
        #pragma unroll
        for (int jj = 0; jj < 16; ++jj) {
            float* wb = wb2[jj & 1];
            if (w == q) wb[c] = a_loc[jj];       // publish trailing row j
            __syncthreads();
            const int j = q * 16 + jj;
            float ajc = wb[c];
            float d   = wb[j];
            float sq  = sqrtf(d);
            float rsq = __builtin_amdgcn_rcpf(sq);
            float rd  = __builtin_amdgcn_rcpf(d);
            logdiag += 0.5f * __logf(d);
            if (w == q) rsq_loc[jj] = rsq;
            LT[j][c] = ajc * rsq;
            float beta = ajc * rd;
            const float4* wv = (const float4*)(wb + w * 16);
            #pragma unroll
            for (int rr = 0; rr < 16; rr += 4) {
                float4 v = wv[rr >> 2];
                a_loc[rr]     = fmaf(-v.x, beta, a_loc[rr]);
                a_loc[rr + 1] = fmaf(-v.y, beta, a_loc[rr + 1]);
                a_loc[rr + 2] = fmaf(-v.z, beta, a_loc[rr + 2]);
                a_loc[rr + 3] = fmaf(-v.w, beta, a_loc[rr + 3]);
            }
        }
    }

    float s_loc[16];
    #pragma unroll
    for (int r = 0; r < 16; ++r)
        s_loc[r] = (w * 16 + r == c) ? 1.0f : 0.0f;

    #pragma unroll 1
    for (int q = 0; q < 4; ++q) {
        #pragma unroll
        for (int ii = 0; ii < 16; ++ii) {
            const int i = q * 16 + ii;
            float* gw = gw2[ii & 1];
            if (w == q) {
                float gv = s_loc[ii] * rsq_loc[ii];
                gw[c] = gv;
                Xs[i][c] = gv;
            }
            __syncthreads();
            float gc = gw[c];
            const float4* lv4 = (const float4*)(&LT[i][w * 16]);
            #pragma unroll
            for (int rr = 0; rr < 16; rr += 4) {
                float4 v = lv4[rr >> 2];
                s_loc[rr]     = fmaf(-v.x, gc, s_loc[rr]);
                s_loc[rr + 1] = fmaf(-v.y, gc, s_loc[rr + 1]);
                s_loc[rr + 2] = fmaf(-v.z, gc, s_loc[rr + 2]);
                s_loc[rr + 3] = fmaf(-v.w, gc, s_loc[rr + 3]);
            }
        }
    }
    __syncthreads();

    // g row c: chunks jb=2w,2w+1, XOR-swizzled (jb ^ (row&7))
    {
        __hip_bfloat16* grow = g + ((long)(k * NF + c)) * NF;
        #pragma unroll
        for (int h = 0; h < 2; ++h) {
            int jb = w * 2 + h;
            bf16x8 v;
            #pragma unroll
            for (int u = 0; u < 8; ++u)
                v[u] = (__bf16)Xs[c][jb * 8 + u];
            *(bf16x8*)(grow + ((jb ^ (c & 7)) * 8)) = v;
        }
    }

    if (w == 0) {
        const float* mu = means + k * NF;
        float a0 = 0.0f, a1 = 0.0f;
        #pragma unroll
        for (int j = 0; j < NF; j += 2) {
            a0 = fmaf(Xs[c][j],     mu[j],     a0);
            a1 = fmaf(Xs[c][j + 1], mu[j + 1], a1);
        }
        t[k * NF + c] = a0 + a1;
        if (c == 0)
            Cc[k] = __logf(weights[k]) - 0.5f * (float)NF * 1.8378770664093453f - logdiag;
    }
}

// ---------------------------------------------------------------------------
// Kernel 2 v9: 32x32x16 MFMA + K-augmentation. Persistent G-in-LDS (128 KiB,
// same swizzled layout), 13 waves/block. Per comp per wave (64 samples):
//   8 swizzled ds_read_b128 (G A-frags, reused across both 32-col tiles)
//   2 ds_read_b32 (nt for the K=64 column of [G | -t])
//   20 MFMA 32x32x16 (incl. the K-augment step vs constant B=[1,0..])
//   in-lane 16 squares/tile + ONE shfl_xor(32)/tile  (was 8 shfls + 4 b128 t)
// DS/comp: 192 -> 108 cyc; per-CU DS floor 16.6 -> 9.4 us.
// C/D layout: col=lane&31, row=(reg&3)+8*(reg>>2)+4*(lane>>5) [m74/m101];
// A: lane: row lane&31, k=(lane>>5)*8+j; B: col lane&31, same k.
// ---------------------------------------------------------------------------
__global__ __launch_bounds__(832, 4) void gmm_main(
    const float* __restrict__ data,
    const char* __restrict__ gsw,         // swizzled bf16 G, [NC][8192 B]
    const float* __restrict__ t,
    const float* __restrict__ Cc,
    float* __restrict__ partials,
    int nTiles, int N, int totalWaves)
{
    __shared__ __align__(16) char gbuf[NC * 8192];   // 128 KiB
    __shared__ __align__(16) float nt_lds[NC * NF];  // negated t
    __shared__ float cc_lds[NC];

    const int tidx = threadIdx.x;
    const int w    = tidx >> 6;
    const int lane = tidx & 63;
    const int l31  = lane & 31;
    const int hi   = lane >> 5;

    // stage G: wave w covers comps {w, w+13}
    for (int i = w; i < NC; i += MAIN_WAVES) {
        const char* src = gsw + (size_t)i * 8192;
        char* dst = gbuf + (size_t)i * 8192;
        #pragma unroll
        for (int u = 0; u < 8; ++u)
            stage16(src + u * 1024 + lane * 16, dst + u * 1024);
    }
    for (int i = tidx; i < NC * NF; i += 832) nt_lds[i] = -t[i];
    if (tidx < NC) cc_lds[tidx] = Cc[tidx];

    const int gid = blockIdx.x * MAIN_WAVES + w;

    // per-lane swizzled G byte offsets: row = mt*32 + l31, chunk = ks*2 + hi
    int offG[2][4];
    #pragma unroll
    for (int mt = 0; mt < 2; ++mt) {
        int row = mt * 32 + l31;
        #pragma unroll
        for (int ks = 0; ks < 4; ++ks)
            offG[mt][ks] = row * 128 + (((ks * 2 + hi) ^ (row & 7)) * 16);
    }

    // constant B-frag for K-augment step: x'[64] = 1 (k=64 lives in hi==0,j=0)
    bf16x8 b4;
    #pragma unroll
    for (int u = 0; u < 8; ++u) b4[u] = (__bf16)0.0f;
    if (hi == 0) b4[0] = (__bf16)1.0f;

    // B-frags: xf[ct][ks]: sample = base + ct*32 + l31, k = ks*16 + hi*8 + j
    bf16x8 xf[2][4];
    auto loadx = [&](long base) {
        #pragma unroll
        for (int ct = 0; ct < 2; ++ct) {
            long row = base + ct * 32 + l31;
            if (row > (long)N - 1) row = (long)N - 1;
            const float* xp = data + row * NF + hi * 8;
            #pragma unroll
            for (int ks = 0; ks < 4; ++ks) {
                float4 p0 = *(const float4*)(xp + ks * 16);
                float4 p1 = *(const float4*)(xp + ks * 16 + 4);
                bf16x8 f;
                f[0] = (__bf16)p0.x; f[1] = (__bf16)p0.y;
                f[2] = (__bf16)p0.z; f[3] = (__bf16)p0.w;
                f[4] = (__bf16)p1.x; f[5] = (__bf16)p1.y;
                f[6] = (__bf16)p1.z; f[7] = (__bf16)p1.w;
                xf[ct][ks] = f;
            }
        }
    };

    if (gid < nTiles) loadx((long)gid * 64);   // overlaps staging flight

    __syncthreads();   // G + t staged; only barrier in the kernel

    float wavePartial = 0.0f;

    #pragma unroll 1
    for (int tile = gid; tile < nTiles; tile += totalWaves) {
        const long base = (long)tile * 64;
        if (tile != gid) loadx(base);

        float m0 = -INFINITY, m1 = -INFINITY, s0 = 0.0f, s1 = 0.0f;

        #pragma unroll 2
        for (int kk = 0; kk < NC; ++kk) {
            // A-frags for the K-augment step: elem0 = -t[row] on hi==0 lanes
            float tv0 = nt_lds[kk * NF + l31];
            float tv1 = nt_lds[kk * NF + 32 + l31];
            bf16x8 a4m0, a4m1;
            #pragma unroll
            for (int u = 0; u < 8; ++u) { a4m0[u] = (__bf16)0.0f; a4m1[u] = (__bf16)0.0f; }
            if (hi == 0) { a4m0[0] = (__bf16)tv0; a4m1[0] = (__bf16)tv1; }

            float mah0 = 0.0f, mah1 = 0.0f;
            const char* gk = gbuf + kk * 8192;
            #pragma unroll
            for (int mt = 0; mt < 2; ++mt) {
                bf16x8 gA0 = *(const bf16x8*)(gk + offG[mt][0]);
                bf16x8 gA1 = *(const bf16x8*)(gk + offG[mt][1]);
                bf16x8 gA2 = *(const bf16x8*)(gk + offG[mt][2]);
                bf16x8 gA3 = *(const bf16x8*)(gk + offG[mt][3]);
                bf16x8 a4  = mt ? a4m1 : a4m0;       // static (mt unrolled)
                #pragma unroll
                for (int ct = 0; ct < 2; ++ct) {
                    f32x16 acc;
                    #pragma unroll
                    for (int u = 0; u < 16; ++u) acc[u] = 0.0f;
                    acc = __builtin_amdgcn_mfma_f32_32x32x16_bf16(gA0, xf[ct][0], acc, 0, 0, 0);
                    acc = __builtin_amdgcn_mfma_f32_32x32x16_bf16(gA1, xf[ct][1], acc, 0, 0, 0);
                    acc = __builtin_amdgcn_mfma_f32_32x32x16_bf16(gA2, xf[ct][2], acc, 0, 0, 0);
                    acc = __builtin_amdgcn_mfma_f32_32x32x16_bf16(gA3, xf[ct][3], acc, 0, 0, 0);
                    acc = __builtin_amdgcn_mfma_f32_32x32x16_bf16(a4,  b4,        acc, 0, 0, 0);
                    float q0 = 0.0f, q1 = 0.0f, q2 = 0.0f, q3 = 0.0f;
                    #pragma unroll
                    for (int u = 0; u < 16; u += 4) {
                        q0 = fmaf(acc[u],     acc[u],     q0);
                        q1 = fmaf(acc[u + 1], acc[u + 1], q1);
                        q2 = fmaf(acc[u + 2], acc[u + 2], q2);
                        q3 = fmaf(acc[u + 3], acc[u + 3], q3);
                    }
                    float qs = (q0 + q1) + (q2 + q3);
                    if (ct == 0) mah0 += qs; else mah1 += qs;
                }
            }
            // complementary row-halves live in lanes l and l^32
            mah0 += __shfl_xor(mah0, 32);
            mah1 += __shfl_xor(mah1, 32);

            float Ck = cc_lds[kk];
            {
                float wlp = fmaf(-0.5f, mah0, Ck);
                float mn = fmaxf(m0, wlp);
                s0 = s0 * __expf(m0 - mn) + __expf(wlp - mn);
                m0 = mn;
            }
            {
                float wlp = fmaf(-0.5f, mah1, Ck);
                float mn = fmaxf(m1, wlp);
                s1 = s1 * __expf(m1 - mn) + __expf(wlp - mn);
                m1 = mn;
            }
        }

        if (hi == 0) {     // lanes 0..31 hold the 2x32 distinct samples
            long sid0 = base + l31;
            long sid1 = base + 32 + l31;
            if (sid0 < (long)N) wavePartial += m0 + __logf(s0);
            if (sid1 < (long)N) wavePartial += m1 + __logf(s1);
        }
    }

    #pragma unroll
    for (int off = 1; off < 64; off <<= 1)
        wavePartial += __shfl_xor(wavePartial, off);
    if (lane == 0)
        partials[gid] = wavePartial;
}

// ---------------------------------------------------------------------------
// Kernel 3: deterministic final reduction over per-wave partials.
// ---------------------------------------------------------------------------
__global__ __launch_bounds__(256) void gmm_reduce(
    const float* __restrict__ partials, int n, float* __restrict__ out)
{
    float s = 0.0f;
    for (int i = threadIdx.x; i < n; i += 256)
        s += partials[i];
    #pragma unroll
    for (int off = 1; off < 64; off <<= 1)
        s += __shfl_xor(s, off);
    __shared__ float sm[4];
    const int wave = threadIdx.x >> 6;
    const int lane = threadIdx.x & 63;
    if (lane == 0) sm[wave] = s;
    __syncthreads();
    if (threadIdx.x == 0)
        out[0] = (sm[0] + sm[1]) + (sm[2] + sm[3]);
}

// ---------------------------------------------------------------------------
extern "C" void kernel_launch(void* const* d_in, const int* in_sizes, int n_in,
                              void* d_out, int out_size, void* d_ws, size_t ws_size,
                              hipStream_t stream)
{
    const float* data    = (const float*)d_in[0];
    const float* weights = (const float*)d_in[1];
    const float* means   = (const float*)d_in[2];
    const float* cov     = (const float*)d_in[3];

    const int N = in_sizes[0] / NF;

    char* ws = (char*)d_ws;
    __hip_bfloat16* g = (__hip_bfloat16*)ws;                    // 131072 B (swizzled)
    float* t          = (float*)(ws + 131072);                  // 4096 B
    float* Cc         = (float*)(ws + 131072 + 4096);           // 64 B
    float* partials   = (float*)(ws + 131072 + 4096 + 64);      // totalWaves * 4 B

    const int nTiles     = (N + 63) / 64;
    const int totalWaves = MAIN_BLOCKS * MAIN_WAVES;

    gmm_precompute<<<NC, 256, 0, stream>>>(cov, means, weights, g, t, Cc);
    gmm_main<<<MAIN_BLOCKS, 64 * MAIN_WAVES, 0, stream>>>(
        data, (const char*)g, t, Cc, partials, nTiles, N, totalWaves);
    gmm_reduce<<<1, 256, 0, stream>>>(partials, totalWaves, (float*)d_out);
}

// Round 10
// 76.956 us; speedup vs baseline: 1.0109x; 1.0109x over previous
//
#include <hip/hip_runtime.h>
#include <hip/hip_bf16.h>
#include <math.h>

#define NF 64
#define NC 16
#define MAIN_BLOCKS 256
#define MAIN_WAVES  13                 // 832 thr; 3328 waves vs 3125 tiles

typedef __bf16 bf16x8 __attribute__((ext_vector_type(8)));
typedef float f32x4 __attribute__((ext_vector_type(4)));
typedef float f32x16 __attribute__((ext_vector_type(16)));
typedef unsigned int u32;

// async global->LDS, 16B/lane. LDS dest = wave-uniform base (HW adds lane*16).
__device__ __forceinline__ void stage16(const void* gsrc, void* ldst) {
    __builtin_amdgcn_global_load_lds(
        (const __attribute__((address_space(1))) u32*)gsrc,
        (__attribute__((address_space(3))) u32*)ldst,
        16, 0, 0);
}

// ---------------------------------------------------------------------------
// Kernel 1 v8 (unchanged): 4-wave cooperative Cholesky + inverse, rolled
// phase loops (L1I-resident ~13KB). See round-8 notes.
// ---------------------------------------------------------------------------
__global__ __launch_bounds__(256) void gmm_precompute(
    const float* __restrict__ cov,
    const float* __restrict__ means,
    const float* __restrict__ weights,
    __hip_bfloat16* __restrict__ g,
    float* __restrict__ t,
    float* __restrict__ Cc)
{
    const int w = threadIdx.x >> 6;   // wave 0..3: rows [16w,16w+16)
    const int c = threadIdx.x & 63;   // lane owns column c
    const int k = blockIdx.x;

    __shared__ __align__(16) float LT[NF][68];   // LT[j][r] = L[r][j]
    __shared__ float Xs[NF][65];                 // Xs[i][c] = G[i][c]
    __shared__ __align__(16) float wb2[2][68];   // ping-pong published row
    __shared__ __align__(16) float gw2[2][68];   // ping-pong published G row

    float a_loc[16];
    {
        const float* src = cov + (long)k * NF * NF + (w * 16) * NF + c;
        #pragma unroll
        for (int r = 0; r < 16; ++r)
            a_loc[r] = src[r * NF];
    }

    float rsq_loc[16];
    float logdiag = 0.0f;

    #pragma unroll 1
    for (int q = 0; q < 4; ++q) {
        #pragma unroll
        for (int jj = 0; jj < 16; ++jj) {
            float* wb = wb2[jj & 1];
            if (w == q) wb[c] = a_loc[jj];       // publish trailing row j
            __syncthreads();
            const int j = q * 16 + jj;
            float ajc = wb[c];
            float d   = wb[j];
            float sq  = sqrtf(d);
            float rsq = __builtin_amdgcn_rcpf(sq);
            float rd  = __builtin_amdgcn_rcpf(d);
            logdiag += 0.5f * __logf(d);
            if (w == q) rsq_loc[jj] = rsq;
            LT[j][c] = ajc * rsq;
            float beta = ajc * rd;
            const float4* wv = (const float4*)(wb + w * 16);
            #pragma unroll
            for (int rr = 0; rr < 16; rr += 4) {
                float4 v = wv[rr >> 2];
                a_loc[rr]     = fmaf(-v.x, beta, a_loc[rr]);
                a_loc[rr + 1] = fmaf(-v.y, beta, a_loc[rr + 1]);
                a_loc[rr + 2] = fmaf(-v.z, beta, a_loc[rr + 2]);
                a_loc[rr + 3] = fmaf(-v.w, beta, a_loc[rr + 3]);
            }
        }
    }

    float s_loc[16];
    #pragma unroll
    for (int r = 0; r < 16; ++r)
        s_loc[r] = (w * 16 + r == c) ? 1.0f : 0.0f;

    #pragma unroll 1
    for (int q = 0; q < 4; ++q) {
        #pragma unroll
        for (int ii = 0; ii < 16; ++ii) {
            const int i = q * 16 + ii;
            float* gw = gw2[ii & 1];
            if (w == q) {
                float gv = s_loc[ii] * rsq_loc[ii];
                gw[c] = gv;
                Xs[i][c] = gv;
            }
            __syncthreads();
            float gc = gw[c];
            const float4* lv4 = (const float4*)(&LT[i][w * 16]);
            #pragma unroll
            for (int rr = 0; rr < 16; rr += 4) {
                float4 v = lv4[rr >> 2];
                s_loc[rr]     = fmaf(-v.x, gc, s_loc[rr]);
                s_loc[rr + 1] = fmaf(-v.y, gc, s_loc[rr + 1]);
                s_loc[rr + 2] = fmaf(-v.z, gc, s_loc[rr + 2]);
                s_loc[rr + 3] = fmaf(-v.w, gc, s_loc[rr + 3]);
            }
        }
    }
    __syncthreads();

    // g row c: chunks jb=2w,2w+1, XOR-swizzled (jb ^ (row&7))
    {
        __hip_bfloat16* grow = g + ((long)(k * NF + c)) * NF;
        #pragma unroll
        for (int h = 0; h < 2; ++h) {
            int jb = w * 2 + h;
            bf16x8 v;
            #pragma unroll
            for (int u = 0; u < 8; ++u)
                v[u] = (__bf16)Xs[c][jb * 8 + u];
            *(bf16x8*)(grow + ((jb ^ (c & 7)) * 8)) = v;
        }
    }

    if (w == 0) {
        const float* mu = means + k * NF;
        float a0 = 0.0f, a1 = 0.0f;
        #pragma unroll
        for (int j = 0; j < NF; j += 2) {
            a0 = fmaf(Xs[c][j],     mu[j],     a0);
            a1 = fmaf(Xs[c][j + 1], mu[j + 1], a1);
        }
        t[k * NF + c] = a0 + a1;
        if (c == 0)
            Cc[k] = __logf(weights[k]) - 0.5f * (float)NF * 1.8378770664093453f - logdiag;
    }
}

// ---------------------------------------------------------------------------
// Kernel 2 v10: identical to v9 except __launch_bounds__(832) (no min-waves).
// v9's (832,4) made the compiler budget for 2 co-resident blocks (26 waves ->
// 7/EU -> 64-VGPR class) -> ~100-VGPR working set spilled to scratch
// (WRITE_SIZE 20KB -> 8.7MB). Plain (832) caps at 128 VGPR (13 waves -> 4 on
// fullest SIMD), which fits the working set spill-free.
// ---------------------------------------------------------------------------
__global__ __launch_bounds__(832) void gmm_main(
    const float* __restrict__ data,
    const char* __restrict__ gsw,         // swizzled bf16 G, [NC][8192 B]
    const float* __restrict__ t,
    const float* __restrict__ Cc,
    float* __restrict__ partials,
    int nTiles, int N, int totalWaves)
{
    __shared__ __align__(16) char gbuf[NC * 8192];   // 128 KiB
    __shared__ __align__(16) float nt_lds[NC * NF];  // negated t
    __shared__ float cc_lds[NC];

    const int tidx = threadIdx.x;
    const int w    = tidx >> 6;
    const int lane = tidx & 63;
    const int l31  = lane & 31;
    const int hi   = lane >> 5;

    // stage G: wave w covers comps {w, w+13}
    for (int i = w; i < NC; i += MAIN_WAVES) {
        const char* src = gsw + (size_t)i * 8192;
        char* dst = gbuf + (size_t)i * 8192;
        #pragma unroll
        for (int u = 0; u < 8; ++u)
            stage16(src + u * 1024 + lane * 16, dst + u * 1024);
    }
    for (int i = tidx; i < NC * NF; i += 832) nt_lds[i] = -t[i];
    if (tidx < NC) cc_lds[tidx] = Cc[tidx];

    const int gid = blockIdx.x * MAIN_WAVES + w;

    // per-lane swizzled G byte offsets: row = mt*32 + l31, chunk = ks*2 + hi
    int offG[2][4];
    #pragma unroll
    for (int mt = 0; mt < 2; ++mt) {
        int row = mt * 32 + l31;
        #pragma unroll
        for (int ks = 0; ks < 4; ++ks)
            offG[mt][ks] = row * 128 + (((ks * 2 + hi) ^ (row & 7)) * 16);
    }

    // constant B-frag for K-augment step: x'[64] = 1 (k=64 lives in hi==0,j=0)
    bf16x8 b4;
    #pragma unroll
    for (int u = 0; u < 8; ++u) b4[u] = (__bf16)0.0f;
    if (hi == 0) b4[0] = (__bf16)1.0f;

    // B-frags: xf[ct][ks]: sample = base + ct*32 + l31, k = ks*16 + hi*8 + j
    bf16x8 xf[2][4];
    auto loadx = [&](long base) {
        #pragma unroll
        for (int ct = 0; ct < 2; ++ct) {
            long row = base + ct * 32 + l31;
            if (row > (long)N - 1) row = (long)N - 1;
            const float* xp = data + row * NF + hi * 8;
            #pragma unroll
            for (int ks = 0; ks < 4; ++ks) {
                float4 p0 = *(const float4*)(xp + ks * 16);
                float4 p1 = *(const float4*)(xp + ks * 16 + 4);
                bf16x8 f;
                f[0] = (__bf16)p0.x; f[1] = (__bf16)p0.y;
                f[2] = (__bf16)p0.z; f[3] = (__bf16)p0.w;
                f[4] = (__bf16)p1.x; f[5] = (__bf16)p1.y;
                f[6] = (__bf16)p1.z; f[7] = (__bf16)p1.w;
                xf[ct][ks] = f;
            }
        }
    };

    if (gid < nTiles) loadx((long)gid * 64);   // overlaps staging flight

    __syncthreads();   // G + t staged; only barrier in the kernel

    float wavePartial = 0.0f;

    #pragma unroll 1
    for (int tile = gid; tile < nTiles; tile += totalWaves) {
        const long base = (long)tile * 64;
        if (tile != gid) loadx(base);

        float m0 = -INFINITY, m1 = -INFINITY, s0 = 0.0f, s1 = 0.0f;

        #pragma unroll 2
        for (int kk = 0; kk < NC; ++kk) {
            // A-frags for the K-augment step: elem0 = -t[row] on hi==0 lanes
            float tv0 = nt_lds[kk * NF + l31];
            float tv1 = nt_lds[kk * NF + 32 + l31];
            bf16x8 a4m0, a4m1;
            #pragma unroll
            for (int u = 0; u < 8; ++u) { a4m0[u] = (__bf16)0.0f; a4m1[u] = (__bf16)0.0f; }
            if (hi == 0) { a4m0[0] = (__bf16)tv0; a4m1[0] = (__bf16)tv1; }

            float mah0 = 0.0f, mah1 = 0.0f;
            const char* gk = gbuf + kk * 8192;
            #pragma unroll
            for (int mt = 0; mt < 2; ++mt) {
                bf16x8 gA0 = *(const bf16x8*)(gk + offG[mt][0]);
                bf16x8 gA1 = *(const bf16x8*)(gk + offG[mt][1]);
                bf16x8 gA2 = *(const bf16x8*)(gk + offG[mt][2]);
                bf16x8 gA3 = *(const bf16x8*)(gk + offG[mt][3]);
                bf16x8 a4  = mt ? a4m1 : a4m0;       // static (mt unrolled)
                #pragma unroll
                for (int ct = 0; ct < 2; ++ct) {
                    f32x16 acc;
                    #pragma unroll
                    for (int u = 0; u < 16; ++u) acc[u] = 0.0f;
                    acc = __builtin_amdgcn_mfma_f32_32x32x16_bf16(gA0, xf[ct][0], acc, 0, 0, 0);
                    acc = __builtin_amdgcn_mfma_f32_32x32x16_bf16(gA1, xf[ct][1], acc, 0, 0, 0);
                    acc = __builtin_amdgcn_mfma_f32_32x32x16_bf16(gA2, xf[ct][2], acc, 0, 0, 0);
                    acc = __builtin_amdgcn_mfma_f32_32x32x16_bf16(gA3, xf[ct][3], acc, 0, 0, 0);
                    acc = __builtin_amdgcn_mfma_f32_32x32x16_bf16(a4,  b4,        acc, 0, 0, 0);
                    float q0 = 0.0f, q1 = 0.0f, q2 = 0.0f, q3 = 0.0f;
                    #pragma unroll
                    for (int u = 0; u < 16; u += 4) {
                        q0 = fmaf(acc[u],     acc[u],     q0);
                        q1 = fmaf(acc[u + 1], acc[u + 1], q1);
                        q2 = fmaf(acc[u + 2], acc[u + 2], q2);
                        q3 = fmaf(acc[u + 3], acc[u + 3], q3);
                    }
                    float qs = (q0 + q1) + (q2 + q3);
                    if (ct == 0) mah0 += qs; else mah1 += qs;
                }
            }
            // complementary row-halves live in lanes l and l^32
            mah0 += __shfl_xor(mah0, 32);
            mah1 += __shfl_xor(mah1, 32);

            float Ck = cc_lds[kk];
            {
                float wlp = fmaf(-0.5f, mah0, Ck);
                float mn = fmaxf(m0, wlp);
                s0 = s0 * __expf(m0 - mn) + __expf(wlp - mn);
                m0 = mn;
            }
            {
                float wlp = fmaf(-0.5f, mah1, Ck);
                float mn = fmaxf(m1, wlp);
                s1 = s1 * __expf(m1 - mn) + __expf(wlp - mn);
                m1 = mn;
            }
        }

        if (hi == 0) {     // lanes 0..31 hold the 2x32 distinct samples
            long sid0 = base + l31;
            long sid1 = base + 32 + l31;
            if (sid0 < (long)N) wavePartial += m0 + __logf(s0);
            if (sid1 < (long)N) wavePartial += m1 + __logf(s1);
        }
    }

    #pragma unroll
    for (int off = 1; off < 64; off <<= 1)
        wavePartial += __shfl_xor(wavePartial, off);
    if (lane == 0)
        partials[gid] = wavePartial;
}

// ---------------------------------------------------------------------------
// Kernel 3: deterministic final reduction over per-wave partials.
// ---------------------------------------------------------------------------
__global__ __launch_bounds__(256) void gmm_reduce(
    const float* __restrict__ partials, int n, float* __restrict__ out)
{
    float s = 0.0f;
    for (int i = threadIdx.x; i < n; i += 256)
        s += partials[i];
    #pragma unroll
    for (int off = 1; off < 64; off <<= 1)
        s += __shfl_xor(s, off);
    __shared__ float sm[4];
    const int wave = threadIdx.x >> 6;
    const int lane = threadIdx.x & 63;
    if (lane == 0) sm[wave] = s;
    __syncthreads();
    if (threadIdx.x == 0)
        out[0] = (sm[0] + sm[1]) + (sm[2] + sm[3]);
}

// ---------------------------------------------------------------------------
extern "C" void kernel_launch(void* const* d_in, const int* in_sizes, int n_in,
                              void* d_out, int out_size, void* d_ws, size_t ws_size,
                              hipStream_t stream)
{
    const float* data    = (const float*)d_in[0];
    const float* weights = (const float*)d_in[1];
    const float* means   = (const float*)d_in[2];
    const float* cov     = (const float*)d_in[3];

    const int N = in_sizes[0] / NF;

    char* ws = (char*)d_ws;
    __hip_bfloat16* g = (__hip_bfloat16*)ws;                    // 131072 B (swizzled)
    float* t          = (float*)(ws + 131072);                  // 4096 B
    float* Cc         = (float*)(ws + 131072 + 4096);           // 64 B
    float* partials   = (float*)(ws + 131072 + 4096 + 64);      // totalWaves * 4 B

    const int nTiles     = (N + 63) / 64;
    const int totalWaves = MAIN_BLOCKS * MAIN_WAVES;

    gmm_precompute<<<NC, 256, 0, stream>>>(cov, means, weights, g, t, Cc);
    gmm_main<<<MAIN_BLOCKS, 64 * MAIN_WAVES, 0, stream>>>(
        data, (const char*)g, t, Cc, partials, nTiles, N, totalWaves);
    gmm_reduce<<<1, 256, 0, stream>>>(partials, totalWaves, (float*)d_out);
}

// Round 11
// 67.110 us; speedup vs baseline: 1.1592x; 1.1467x over previous
//
#include <hip/hip_runtime.h>
#include <hip/hip_bf16.h>
#include <math.h>

#define NF 64
#define NC 16
#define MAIN_BLOCKS 256
#define MAIN_WAVES  16                 // 1024 thr; 4096 waves vs 3125 tiles
#define TPW 4                          // 16-sample subtiles per wave (64 samples)

typedef __bf16 bf16x8 __attribute__((ext_vector_type(8)));
typedef float f32x4 __attribute__((ext_vector_type(4)));
typedef unsigned int u32;

// async global->LDS, 16B/lane. LDS dest = wave-uniform base (HW adds lane*16).
__device__ __forceinline__ void stage16(const void* gsrc, void* ldst) {
    __builtin_amdgcn_global_load_lds(
        (const __attribute__((address_space(1))) u32*)gsrc,
        (__attribute__((address_space(3))) u32*)ldst,
        16, 0, 0);
}

// ---------------------------------------------------------------------------
// Kernel 1 v8 (unchanged): 4-wave cooperative Cholesky + inverse, rolled
// phase loops (L1I-resident ~13KB). See round-8 notes.
// ---------------------------------------------------------------------------
__global__ __launch_bounds__(256) void gmm_precompute(
    const float* __restrict__ cov,
    const float* __restrict__ means,
    const float* __restrict__ weights,
    __hip_bfloat16* __restrict__ g,
    float* __restrict__ t,
    float* __restrict__ Cc)
{
    const int w = threadIdx.x >> 6;   // wave 0..3: rows [16w,16w+16)
    const int c = threadIdx.x & 63;   // lane owns column c
    const int k = blockIdx.x;

    __shared__ __align__(16) float LT[NF][68];   // LT[j][r] = L[r][j]
    __shared__ float Xs[NF][65];                 // Xs[i][c] = G[i][c]
    __shared__ __align__(16) float wb2[2][68];   // ping-pong published row
    __shared__ __align__(16) float gw2[2][68];   // ping-pong published G row

    float a_loc[16];
    {
        const float* src = cov + (long)k * NF * NF + (w * 16) * NF + c;
        #pragma unroll
        for (int r = 0; r < 16; ++r)
            a_loc[r] = src[r * NF];
    }

    float rsq_loc[16];
    float logdiag = 0.0f;

    #pragma unroll 1
    for (int q = 0; q < 4; ++q) {
        #pragma unroll
        for (int jj = 0; jj < 16; ++jj) {
            float* wb = wb2[jj & 1];
            if (w == q) wb[c] = a_loc[jj];       // publish trailing row j
            __syncthreads();
            const int j = q * 16 + jj;
            float ajc = wb[c];
            float d   = wb[j];
            float sq  = sqrtf(d);
            float rsq = __builtin_amdgcn_rcpf(sq);
            float rd  = __builtin_amdgcn_rcpf(d);
            logdiag += 0.5f * __logf(d);
            if (w == q) rsq_loc[jj] = rsq;
            LT[j][c] = ajc * rsq;
            float beta = ajc * rd;
            const float4* wv = (const float4*)(wb + w * 16);
            #pragma unroll
            for (int rr = 0; rr < 16; rr += 4) {
                float4 v = wv[rr >> 2];
                a_loc[rr]     = fmaf(-v.x, beta, a_loc[rr]);
                a_loc[rr + 1] = fmaf(-v.y, beta, a_loc[rr + 1]);
                a_loc[rr + 2] = fmaf(-v.z, beta, a_loc[rr + 2]);
                a_loc[rr + 3] = fmaf(-v.w, beta, a_loc[rr + 3]);
            }
        }
    }

    float s_loc[16];
    #pragma unroll
    for (int r = 0; r < 16; ++r)
        s_loc[r] = (w * 16 + r == c) ? 1.0f : 0.0f;

    #pragma unroll 1
    for (int q = 0; q < 4; ++q) {
        #pragma unroll
        for (int ii = 0; ii < 16; ++ii) {
            const int i = q * 16 + ii;
            float* gw = gw2[ii & 1];
            if (w == q) {
                float gv = s_loc[ii] * rsq_loc[ii];
                gw[c] = gv;
                Xs[i][c] = gv;
            }
            __syncthreads();
            float gc = gw[c];
            const float4* lv4 = (const float4*)(&LT[i][w * 16]);
            #pragma unroll
            for (int rr = 0; rr < 16; rr += 4) {
                float4 v = lv4[rr >> 2];
                s_loc[rr]     = fmaf(-v.x, gc, s_loc[rr]);
                s_loc[rr + 1] = fmaf(-v.y, gc, s_loc[rr + 1]);
                s_loc[rr + 2] = fmaf(-v.z, gc, s_loc[rr + 2]);
                s_loc[rr + 3] = fmaf(-v.w, gc, s_loc[rr + 3]);
            }
        }
    }
    __syncthreads();

    // g row c: chunks jb=2w,2w+1, XOR-swizzled (jb ^ (row&7))
    {
        __hip_bfloat16* grow = g + ((long)(k * NF + c)) * NF;
        #pragma unroll
        for (int h = 0; h < 2; ++h) {
            int jb = w * 2 + h;
            bf16x8 v;
            #pragma unroll
            for (int u = 0; u < 8; ++u)
                v[u] = (__bf16)Xs[c][jb * 8 + u];
            *(bf16x8*)(grow + ((jb ^ (c & 7)) * 8)) = v;
        }
    }

    if (w == 0) {
        const float* mu = means + k * NF;
        float a0 = 0.0f, a1 = 0.0f;
        #pragma unroll
        for (int j = 0; j < NF; j += 2) {
            a0 = fmaf(Xs[c][j],     mu[j],     a0);
            a1 = fmaf(Xs[c][j + 1], mu[j + 1], a1);
        }
        t[k * NF + c] = a0 + a1;
        if (c == 0)
            Cc[k] = __logf(weights[k]) - 0.5f * (float)NF * 1.8378770664093453f - logdiag;
    }
}

// ---------------------------------------------------------------------------
// Kernel 2 v11: v8's 16x16 structure (proven 0-conflict swizzle) plus:
//  - TRIANGULAR SKIP: G = L^{-1} is lower-triangular, so row-blocks 0,1
//    (rows 0..31) have all-zero cols 32..63 -> skip the gb read + 2nd MFMA
//    for rc<2. DS 12->10 b128/comp, MFMA 32->24/comp.
//  - COMP STAGGER: wave w walks comps in order (i+w)&15 -> the 16 waves
//    hit DS/MFMA/VALU pipes out of phase instead of convoying (LSE is
//    order-commutative).
//  - 16 waves/block, 256 blocks: all CUs, ~12.2 active waves/CU avg.
// ---------------------------------------------------------------------------
__global__ __launch_bounds__(1024) void gmm_main(
    const float* __restrict__ data,
    const char* __restrict__ gsw,         // swizzled bf16 G, [NC][8192 B]
    const float* __restrict__ t,
    const float* __restrict__ Cc,
    float* __restrict__ partials,
    int nTiles, int N, int totalWaves)
{
    __shared__ __align__(16) char gbuf[NC * 8192];   // 128 KiB
    __shared__ __align__(16) float nt_lds[NC * NF];  // negated t
    __shared__ float cc_lds[NC];

    const int tidx = threadIdx.x;
    const int w    = tidx >> 6;
    const int lane = tidx & 63;
    const int l15  = lane & 15;
    const int lg   = lane >> 4;

    // wave w stages component w (8 KB = 8 x 1KB stage16)
    {
        const char* src = gsw + (size_t)w * 8192;
        char* dst = gbuf + (size_t)w * 8192;
        #pragma unroll
        for (int u = 0; u < 8; ++u)
            stage16(src + u * 1024 + lane * 16, dst + u * 1024);
    }

    nt_lds[tidx] = -t[tidx];                 // 1024 threads, 1024 floats
    if (tidx < NC) cc_lds[tidx] = Cc[tidx];

    const int gid = blockIdx.x * MAIN_WAVES + w;

    // swizzled LDS byte offsets (static per lane)
    int offA[4], offB[4];
    #pragma unroll
    for (int rc = 0; rc < 4; ++rc) {
        int row = rc * 16 + l15;
        offA[rc] = row * 128 + ((lg       ^ (l15 & 7)) * 16);
        offB[rc] = row * 128 + (((lg + 4) ^ (l15 & 7)) * 16);
    }

    // first tile's x fragments (overlaps the staging flight)
    bf16x8 xf[TPW][2];
    if (gid < nTiles) {
        const long base = (long)gid * (TPW * 16);
        #pragma unroll
        for (int st = 0; st < TPW; ++st) {
            long row = base + st * 16 + l15;
            if (row > (long)N - 1) row = (long)N - 1;
            const float* xp = data + row * NF + lg * 8;
            float4 a0 = *(const float4*)(xp);
            float4 a1 = *(const float4*)(xp + 4);
            float4 b0 = *(const float4*)(xp + 32);
            float4 b1 = *(const float4*)(xp + 36);
            bf16x8 f0, f1;
            f0[0] = (__bf16)a0.x; f0[1] = (__bf16)a0.y;
            f0[2] = (__bf16)a0.z; f0[3] = (__bf16)a0.w;
            f0[4] = (__bf16)a1.x; f0[5] = (__bf16)a1.y;
            f0[6] = (__bf16)a1.z; f0[7] = (__bf16)a1.w;
            f1[0] = (__bf16)b0.x; f1[1] = (__bf16)b0.y;
            f1[2] = (__bf16)b0.z; f1[3] = (__bf16)b0.w;
            f1[4] = (__bf16)b1.x; f1[5] = (__bf16)b1.y;
            f1[6] = (__bf16)b1.z; f1[7] = (__bf16)b1.w;
            xf[st][0] = f0;
            xf[st][1] = f1;
        }
    }

    __syncthreads();   // G + t staged; only barrier in the kernel

    float wavePartial = 0.0f;

    #pragma unroll 1
    for (int tile = gid; tile < nTiles; tile += totalWaves) {
        const long base = (long)tile * (TPW * 16);
        if (tile != gid) {     // grid-stride continuation (cold path)
            #pragma unroll
            for (int st = 0; st < TPW; ++st) {
                long row = base + st * 16 + l15;
                if (row > (long)N - 1) row = (long)N - 1;
                const float* xp = data + row * NF + lg * 8;
                float4 a0 = *(const float4*)(xp);
                float4 a1 = *(const float4*)(xp + 4);
                float4 b0 = *(const float4*)(xp + 32);
                float4 b1 = *(const float4*)(xp + 36);
                bf16x8 f0, f1;
                f0[0] = (__bf16)a0.x; f0[1] = (__bf16)a0.y;
                f0[2] = (__bf16)a0.z; f0[3] = (__bf16)a0.w;
                f0[4] = (__bf16)a1.x; f0[5] = (__bf16)a1.y;
                f0[6] = (__bf16)a1.z; f0[7] = (__bf16)a1.w;
                f1[0] = (__bf16)b0.x; f1[1] = (__bf16)b0.y;
                f1[2] = (__bf16)b0.z; f1[3] = (__bf16)b0.w;
                f1[4] = (__bf16)b1.x; f1[5] = (__bf16)b1.y;
                f1[6] = (__bf16)b1.z; f1[7] = (__bf16)b1.w;
                xf[st][0] = f0;
                xf[st][1] = f1;
            }
        }

        float m[TPW], s[TPW];
        #pragma unroll
        for (int st = 0; st < TPW; ++st) { m[st] = -INFINITY; s[st] = 0.0f; }

        #pragma unroll 2
        for (int ii = 0; ii < NC; ++ii) {
            const int kk = (ii + w) & (NC - 1);      // per-wave stagger
            float mah[TPW];
            #pragma unroll
            for (int st = 0; st < TPW; ++st) mah[st] = 0.0f;

            const char* gk = gbuf + kk * 8192;
            const float* ntk = &nt_lds[kk * NF];

            // rc 0,1: rows 0..31 of lower-tri G -> cols 32..63 are ZERO:
            // skip gb read and second MFMA.
            #pragma unroll
            for (int rc = 0; rc < 2; ++rc) {
                bf16x8 ga = *(const bf16x8*)(gk + offA[rc]);
                f32x4 ntv = *(const f32x4*)(ntk + rc * 16 + lg * 4);
                #pragma unroll
                for (int st = 0; st < TPW; ++st) {
                    f32x4 acc = ntv;
                    acc = __builtin_amdgcn_mfma_f32_16x16x32_bf16(ga, xf[st][0], acc, 0, 0, 0);
                    mah[st] = fmaf(acc[0], acc[0], mah[st]);
                    mah[st] = fmaf(acc[1], acc[1], mah[st]);
                    mah[st] = fmaf(acc[2], acc[2], mah[st]);
                    mah[st] = fmaf(acc[3], acc[3], mah[st]);
                }
            }
            // rc 2,3: full rows
            #pragma unroll
            for (int rc = 2; rc < 4; ++rc) {
                bf16x8 ga = *(const bf16x8*)(gk + offA[rc]);
                bf16x8 gb = *(const bf16x8*)(gk + offB[rc]);
                f32x4 ntv = *(const f32x4*)(ntk + rc * 16 + lg * 4);
                #pragma unroll
                for (int st = 0; st < TPW; ++st) {
                    f32x4 acc = ntv;
                    acc = __builtin_amdgcn_mfma_f32_16x16x32_bf16(ga, xf[st][0], acc, 0, 0, 0);
                    acc = __builtin_amdgcn_mfma_f32_16x16x32_bf16(gb, xf[st][1], acc, 0, 0, 0);
                    mah[st] = fmaf(acc[0], acc[0], mah[st]);
                    mah[st] = fmaf(acc[1], acc[1], mah[st]);
                    mah[st] = fmaf(acc[2], acc[2], mah[st]);
                    mah[st] = fmaf(acc[3], acc[3], mah[st]);
                }
            }

            float Ck = cc_lds[kk];
            #pragma unroll
            for (int st = 0; st < TPW; ++st) {
                float v = mah[st];
                v += __shfl_xor(v, 16);
                v += __shfl_xor(v, 32);      // all lanes hold full maha
                float wlp = fmaf(-0.5f, v, Ck);
                float mo = m[st];
                float mn = fmaxf(mo, wlp);
                s[st] = s[st] * __expf(mo - mn) + __expf(wlp - mn);
                m[st] = mn;
            }
        }

        if (lg == 0) {
            #pragma unroll
            for (int st = 0; st < TPW; ++st) {
                long sid = base + st * 16 + l15;
                if (sid < (long)N)
                    wavePartial += m[st] + __logf(s[st]);
            }
        }
    }

    #pragma unroll
    for (int off = 1; off < 64; off <<= 1)
        wavePartial += __shfl_xor(wavePartial, off);
    if (lane == 0)
        partials[gid] = wavePartial;
}

// ---------------------------------------------------------------------------
// Kernel 3: deterministic final reduction over per-wave partials.
// ---------------------------------------------------------------------------
__global__ __launch_bounds__(256) void gmm_reduce(
    const float* __restrict__ partials, int n, float* __restrict__ out)
{
    float s = 0.0f;
    for (int i = threadIdx.x; i < n; i += 256)
        s += partials[i];
    #pragma unroll
    for (int off = 1; off < 64; off <<= 1)
        s += __shfl_xor(s, off);
    __shared__ float sm[4];
    const int wave = threadIdx.x >> 6;
    const int lane = threadIdx.x & 63;
    if (lane == 0) sm[wave] = s;
    __syncthreads();
    if (threadIdx.x == 0)
        out[0] = (sm[0] + sm[1]) + (sm[2] + sm[3]);
}

// ---------------------------------------------------------------------------
extern "C" void kernel_launch(void* const* d_in, const int* in_sizes, int n_in,
                              void* d_out, int out_size, void* d_ws, size_t ws_size,
                              hipStream_t stream)
{
    const float* data    = (const float*)d_in[0];
    const float* weights = (const float*)d_in[1];
    const float* means   = (const float*)d_in[2];
    const float* cov     = (const float*)d_in[3];

    const int N = in_sizes[0] / NF;

    char* ws = (char*)d_ws;
    __hip_bfloat16* g = (__hip_bfloat16*)ws;                    // 131072 B (swizzled)
    float* t          = (float*)(ws + 131072);                  // 4096 B
    float* Cc         = (float*)(ws + 131072 + 4096);           // 64 B
    float* partials   = (float*)(ws + 131072 + 4096 + 64);      // totalWaves * 4 B

    const int nTiles     = (N + TPW * 16 - 1) / (TPW * 16);
    const int totalWaves = MAIN_BLOCKS * MAIN_WAVES;

    gmm_precompute<<<NC, 256, 0, stream>>>(cov, means, weights, g, t, Cc);
    gmm_main<<<MAIN_BLOCKS, 64 * MAIN_WAVES, 0, stream>>>(
        data, (const char*)g, t, Cc, partials, nTiles, N, totalWaves);
    gmm_reduce<<<1, 256, 0, stream>>>(partials, totalWaves, (float*)d_out);
}

// Round 12
// 66.900 us; speedup vs baseline: 1.1628x; 1.0031x over previous
//
#include <hip/hip_runtime.h>
#include <hip/hip_bf16.h>
#include <math.h>

#define NF 64
#define NC 16
#define MAIN_BLOCKS 256
#define MAIN_WAVES  13                 // 832 thr; 3328 waves vs 3125 tiles, all CUs
#define TPW 4                          // 16-sample subtiles per wave (64 samples)

typedef __bf16 bf16x8 __attribute__((ext_vector_type(8)));
typedef float f32x4 __attribute__((ext_vector_type(4)));
typedef unsigned int u32;

// async global->LDS, 16B/lane. LDS dest = wave-uniform base (HW adds lane*16).
__device__ __forceinline__ void stage16(const void* gsrc, void* ldst) {
    __builtin_amdgcn_global_load_lds(
        (const __attribute__((address_space(1))) u32*)gsrc,
        (__attribute__((address_space(3))) u32*)ldst,
        16, 0, 0);
}

// ---------------------------------------------------------------------------
// Kernel 1 v8 (unchanged): 4-wave cooperative Cholesky + inverse, rolled
// phase loops (L1I-resident ~13KB). See round-8 notes.
// ---------------------------------------------------------------------------
__global__ __launch_bounds__(256) void gmm_precompute(
    const float* __restrict__ cov,
    const float* __restrict__ means,
    const float* __restrict__ weights,
    __hip_bfloat16* __restrict__ g,
    float* __restrict__ t,
    float* __restrict__ Cc)
{
    const int w = threadIdx.x >> 6;   // wave 0..3: rows [16w,16w+16)
    const int c = threadIdx.x & 63;   // lane owns column c
    const int k = blockIdx.x;

    __shared__ __align__(16) float LT[NF][68];   // LT[j][r] = L[r][j]
    __shared__ float Xs[NF][65];                 // Xs[i][c] = G[i][c]
    __shared__ __align__(16) float wb2[2][68];   // ping-pong published row
    __shared__ __align__(16) float gw2[2][68];   // ping-pong published G row

    float a_loc[16];
    {
        const float* src = cov + (long)k * NF * NF + (w * 16) * NF + c;
        #pragma unroll
        for (int r = 0; r < 16; ++r)
            a_loc[r] = src[r * NF];
    }

    float rsq_loc[16];
    float logdiag = 0.0f;

    #pragma unroll 1
    for (int q = 0; q < 4; ++q) {
        #pragma unroll
        for (int jj = 0; jj < 16; ++jj) {
            float* wb = wb2[jj & 1];
            if (w == q) wb[c] = a_loc[jj];       // publish trailing row j
            __syncthreads();
            const int j = q * 16 + jj;
            float ajc = wb[c];
            float d   = wb[j];
            float sq  = sqrtf(d);
            float rsq = __builtin_amdgcn_rcpf(sq);
            float rd  = __builtin_amdgcn_rcpf(d);
            logdiag += 0.5f * __logf(d);
            if (w == q) rsq_loc[jj] = rsq;
            LT[j][c] = ajc * rsq;
            float beta = ajc * rd;
            const float4* wv = (const float4*)(wb + w * 16);
            #pragma unroll
            for (int rr = 0; rr < 16; rr += 4) {
                float4 v = wv[rr >> 2];
                a_loc[rr]     = fmaf(-v.x, beta, a_loc[rr]);
                a_loc[rr + 1] = fmaf(-v.y, beta, a_loc[rr + 1]);
                a_loc[rr + 2] = fmaf(-v.z, beta, a_loc[rr + 2]);
                a_loc[rr + 3] = fmaf(-v.w, beta, a_loc[rr + 3]);
            }
        }
    }

    float s_loc[16];
    #pragma unroll
    for (int r = 0; r < 16; ++r)
        s_loc[r] = (w * 16 + r == c) ? 1.0f : 0.0f;

    #pragma unroll 1
    for (int q = 0; q < 4; ++q) {
        #pragma unroll
        for (int ii = 0; ii < 16; ++ii) {
            const int i = q * 16 + ii;
            float* gw = gw2[ii & 1];
            if (w == q) {
                float gv = s_loc[ii] * rsq_loc[ii];
                gw[c] = gv;
                Xs[i][c] = gv;
            }
            __syncthreads();
            float gc = gw[c];
            const float4* lv4 = (const float4*)(&LT[i][w * 16]);
            #pragma unroll
            for (int rr = 0; rr < 16; rr += 4) {
                float4 v = lv4[rr >> 2];
                s_loc[rr]     = fmaf(-v.x, gc, s_loc[rr]);
                s_loc[rr + 1] = fmaf(-v.y, gc, s_loc[rr + 1]);
                s_loc[rr + 2] = fmaf(-v.z, gc, s_loc[rr + 2]);
                s_loc[rr + 3] = fmaf(-v.w, gc, s_loc[rr + 3]);
            }
        }
    }
    __syncthreads();

    // g row c: chunks jb=2w,2w+1, XOR-swizzled (jb ^ (row&7))
    {
        __hip_bfloat16* grow = g + ((long)(k * NF + c)) * NF;
        #pragma unroll
        for (int h = 0; h < 2; ++h) {
            int jb = w * 2 + h;
            bf16x8 v;
            #pragma unroll
            for (int u = 0; u < 8; ++u)
                v[u] = (__bf16)Xs[c][jb * 8 + u];
            *(bf16x8*)(grow + ((jb ^ (c & 7)) * 8)) = v;
        }
    }

    if (w == 0) {
        const float* mu = means + k * NF;
        float a0 = 0.0f, a1 = 0.0f;
        #pragma unroll
        for (int j = 0; j < NF; j += 2) {
            a0 = fmaf(Xs[c][j],     mu[j],     a0);
            a1 = fmaf(Xs[c][j + 1], mu[j + 1], a1);
        }
        t[k * NF + c] = a0 + a1;
        if (c == 0)
            Cc[k] = __logf(weights[k]) - 0.5f * (float)NF * 1.8378770664093453f - logdiag;
    }
}

// ---------------------------------------------------------------------------
// Kernel 2 v12: v11's inner loop (triangular skip + comp stagger, proven
// -26% CU-work) on v8's balanced launch (13 waves/block, 256 blocks ->
// all 256 CUs busy; v11's 16-wave config idled 60 CUs and gave the gain
// back). Persistent G-in-LDS, 0-conflict swizzle, one barrier.
// ---------------------------------------------------------------------------
__global__ __launch_bounds__(832) void gmm_main(
    const float* __restrict__ data,
    const char* __restrict__ gsw,         // swizzled bf16 G, [NC][8192 B]
    const float* __restrict__ t,
    const float* __restrict__ Cc,
    float* __restrict__ partials,
    int nTiles, int N, int totalWaves)
{
    __shared__ __align__(16) char gbuf[NC * 8192];   // 128 KiB
    __shared__ __align__(16) float nt_lds[NC * NF];  // negated t
    __shared__ float cc_lds[NC];

    const int tidx = threadIdx.x;
    const int w    = tidx >> 6;
    const int lane = tidx & 63;
    const int l15  = lane & 15;
    const int lg   = lane >> 4;

    // stage G: wave w covers comps {w, w+13} (<16)
    for (int i = w; i < NC; i += MAIN_WAVES) {
        const char* src = gsw + (size_t)i * 8192;
        char* dst = gbuf + (size_t)i * 8192;
        #pragma unroll
        for (int u = 0; u < 8; ++u)
            stage16(src + u * 1024 + lane * 16, dst + u * 1024);
    }

    for (int i = tidx; i < NC * NF; i += 64 * MAIN_WAVES) nt_lds[i] = -t[i];
    if (tidx < NC) cc_lds[tidx] = Cc[tidx];

    const int gid = blockIdx.x * MAIN_WAVES + w;

    // swizzled LDS byte offsets (static per lane)
    int offA[4], offB[4];
    #pragma unroll
    for (int rc = 0; rc < 4; ++rc) {
        int row = rc * 16 + l15;
        offA[rc] = row * 128 + ((lg       ^ (l15 & 7)) * 16);
        offB[rc] = row * 128 + (((lg + 4) ^ (l15 & 7)) * 16);
    }

    // first tile's x fragments (overlaps the staging flight)
    bf16x8 xf[TPW][2];
    if (gid < nTiles) {
        const long base = (long)gid * (TPW * 16);
        #pragma unroll
        for (int st = 0; st < TPW; ++st) {
            long row = base + st * 16 + l15;
            if (row > (long)N - 1) row = (long)N - 1;
            const float* xp = data + row * NF + lg * 8;
            float4 a0 = *(const float4*)(xp);
            float4 a1 = *(const float4*)(xp + 4);
            float4 b0 = *(const float4*)(xp + 32);
            float4 b1 = *(const float4*)(xp + 36);
            bf16x8 f0, f1;
            f0[0] = (__bf16)a0.x; f0[1] = (__bf16)a0.y;
            f0[2] = (__bf16)a0.z; f0[3] = (__bf16)a0.w;
            f0[4] = (__bf16)a1.x; f0[5] = (__bf16)a1.y;
            f0[6] = (__bf16)a1.z; f0[7] = (__bf16)a1.w;
            f1[0] = (__bf16)b0.x; f1[1] = (__bf16)b0.y;
            f1[2] = (__bf16)b0.z; f1[3] = (__bf16)b0.w;
            f1[4] = (__bf16)b1.x; f1[5] = (__bf16)b1.y;
            f1[6] = (__bf16)b1.z; f1[7] = (__bf16)b1.w;
            xf[st][0] = f0;
            xf[st][1] = f1;
        }
    }

    __syncthreads();   // G + t staged; only barrier in the kernel

    float wavePartial = 0.0f;

    #pragma unroll 1
    for (int tile = gid; tile < nTiles; tile += totalWaves) {
        const long base = (long)tile * (TPW * 16);
        if (tile != gid) {     // grid-stride continuation (cold path)
            #pragma unroll
            for (int st = 0; st < TPW; ++st) {
                long row = base + st * 16 + l15;
                if (row > (long)N - 1) row = (long)N - 1;
                const float* xp = data + row * NF + lg * 8;
                float4 a0 = *(const float4*)(xp);
                float4 a1 = *(const float4*)(xp + 4);
                float4 b0 = *(const float4*)(xp + 32);
                float4 b1 = *(const float4*)(xp + 36);
                bf16x8 f0, f1;
                f0[0] = (__bf16)a0.x; f0[1] = (__bf16)a0.y;
                f0[2] = (__bf16)a0.z; f0[3] = (__bf16)a0.w;
                f0[4] = (__bf16)a1.x; f0[5] = (__bf16)a1.y;
                f0[6] = (__bf16)a1.z; f0[7] = (__bf16)a1.w;
                f1[0] = (__bf16)b0.x; f1[1] = (__bf16)b0.y;
                f1[2] = (__bf16)b0.z; f1[3] = (__bf16)b0.w;
                f1[4] = (__bf16)b1.x; f1[5] = (__bf16)b1.y;
                f1[6] = (__bf16)b1.z; f1[7] = (__bf16)b1.w;
                xf[st][0] = f0;
                xf[st][1] = f1;
            }
        }

        float m[TPW], s[TPW];
        #pragma unroll
        for (int st = 0; st < TPW; ++st) { m[st] = -INFINITY; s[st] = 0.0f; }

        #pragma unroll 2
        for (int ii = 0; ii < NC; ++ii) {
            const int kk = (ii + w) & (NC - 1);      // per-wave stagger
            float mah[TPW];
            #pragma unroll
            for (int st = 0; st < TPW; ++st) mah[st] = 0.0f;

            const char* gk = gbuf + kk * 8192;
            const float* ntk = &nt_lds[kk * NF];

            // rc 0,1: rows 0..31 of lower-tri G -> cols 32..63 are ZERO:
            // skip gb read and second MFMA.
            #pragma unroll
            for (int rc = 0; rc < 2; ++rc) {
                bf16x8 ga = *(const bf16x8*)(gk + offA[rc]);
                f32x4 ntv = *(const f32x4*)(ntk + rc * 16 + lg * 4);
                #pragma unroll
                for (int st = 0; st < TPW; ++st) {
                    f32x4 acc = ntv;
                    acc = __builtin_amdgcn_mfma_f32_16x16x32_bf16(ga, xf[st][0], acc, 0, 0, 0);
                    mah[st] = fmaf(acc[0], acc[0], mah[st]);
                    mah[st] = fmaf(acc[1], acc[1], mah[st]);
                    mah[st] = fmaf(acc[2], acc[2], mah[st]);
                    mah[st] = fmaf(acc[3], acc[3], mah[st]);
                }
            }
            // rc 2,3: full rows
            #pragma unroll
            for (int rc = 2; rc < 4; ++rc) {
                bf16x8 ga = *(const bf16x8*)(gk + offA[rc]);
                bf16x8 gb = *(const bf16x8*)(gk + offB[rc]);
                f32x4 ntv = *(const f32x4*)(ntk + rc * 16 + lg * 4);
                #pragma unroll
                for (int st = 0; st < TPW; ++st) {
                    f32x4 acc = ntv;
                    acc = __builtin_amdgcn_mfma_f32_16x16x32_bf16(ga, xf[st][0], acc, 0, 0, 0);
                    acc = __builtin_amdgcn_mfma_f32_16x16x32_bf16(gb, xf[st][1], acc, 0, 0, 0);
                    mah[st] = fmaf(acc[0], acc[0], mah[st]);
                    mah[st] = fmaf(acc[1], acc[1], mah[st]);
                    mah[st] = fmaf(acc[2], acc[2], mah[st]);
                    mah[st] = fmaf(acc[3], acc[3], mah[st]);
                }
            }

            float Ck = cc_lds[kk];
            #pragma unroll
            for (int st = 0; st < TPW; ++st) {
                float v = mah[st];
                v += __shfl_xor(v, 16);
                v += __shfl_xor(v, 32);      // all lanes hold full maha
                float wlp = fmaf(-0.5f, v, Ck);
                float mo = m[st];
                float mn = fmaxf(mo, wlp);
                s[st] = s[st] * __expf(mo - mn) + __expf(wlp - mn);
                m[st] = mn;
            }
        }

        if (lg == 0) {
            #pragma unroll
            for (int st = 0; st < TPW; ++st) {
                long sid = base + st * 16 + l15;
                if (sid < (long)N)
                    wavePartial += m[st] + __logf(s[st]);
            }
        }
    }

    #pragma unroll
    for (int off = 1; off < 64; off <<= 1)
        wavePartial += __shfl_xor(wavePartial, off);
    if (lane == 0)
        partials[gid] = wavePartial;
}

// ---------------------------------------------------------------------------
// Kernel 3: deterministic final reduction over per-wave partials.
// ---------------------------------------------------------------------------
__global__ __launch_bounds__(256) void gmm_reduce(
    const float* __restrict__ partials, int n, float* __restrict__ out)
{
    float s = 0.0f;
    for (int i = threadIdx.x; i < n; i += 256)
        s += partials[i];
    #pragma unroll
    for (int off = 1; off < 64; off <<= 1)
        s += __shfl_xor(s, off);
    __shared__ float sm[4];
    const int wave = threadIdx.x >> 6;
    const int lane = threadIdx.x & 63;
    if (lane == 0) sm[wave] = s;
    __syncthreads();
    if (threadIdx.x == 0)
        out[0] = (sm[0] + sm[1]) + (sm[2] + sm[3]);
}

// ---------------------------------------------------------------------------
extern "C" void kernel_launch(void* const* d_in, const int* in_sizes, int n_in,
                              void* d_out, int out_size, void* d_ws, size_t ws_size,
                              hipStream_t stream)
{
    const float* data    = (const float*)d_in[0];
    const float* weights = (const float*)d_in[1];
    const float* means   = (const float*)d_in[2];
    const float* cov     = (const float*)d_in[3];

    const int N = in_sizes[0] / NF;

    char* ws = (char*)d_ws;
    __hip_bfloat16* g = (__hip_bfloat16*)ws;                    // 131072 B (swizzled)
    float* t          = (float*)(ws + 131072);                  // 4096 B
    float* Cc         = (float*)(ws + 131072 + 4096);           // 64 B
    float* partials   = (float*)(ws + 131072 + 4096 + 64);      // totalWaves * 4 B

    const int nTiles     = (N + TPW * 16 - 1) / (TPW * 16);
    const int totalWaves = MAIN_BLOCKS * MAIN_WAVES;

    gmm_precompute<<<NC, 256, 0, stream>>>(cov, means, weights, g, t, Cc);
    gmm_main<<<MAIN_BLOCKS, 64 * MAIN_WAVES, 0, stream>>>(
        data, (const char*)g, t, Cc, partials, nTiles, N, totalWaves);
    gmm_reduce<<<1, 256, 0, stream>>>(partials, totalWaves, (float*)d_out);
}